// Round 7
// baseline (244.706 us; speedup 1.0000x reference)
//
#include <hip/hip_runtime.h>

// ---------------------------------------------------------------------------
// FeatureNet: kNN(K=8) relative grouping -> [conv1x1+BN+ReLU] x3 -> max over K
// B=8, N=2048, DIM=128, fp32 in/out.
//
// prep     : fold BN; W1/W2 stored as 4 bf16 planes in MFMA FRAGMENT ORDER
// y        : y[q][f] = W0f . x[q]
// knn_part : 16 ranges x 128 candidates, dual-chain branchless top-8, 1024 WGs
// knn_merge: 4 lanes/query merge 16x8 partials (shfl_xor Batcher merge)
// fused    : PERSISTENT: 256 blocks (1/CU), 8 chunks each, W in 128 VGPRs.
//            A double-buffered LDS, H own region, OS written coalesced at end.
//            XCD-aligned: block bid -> batch bid&7 (1MB y slice per XCD L2).
// ---------------------------------------------------------------------------

#define EPSF 1e-5f
#define FMAXV 3.402823466e+38f

#define NB 8
#define NN 2048
#define KNBR 8
#define DIMF 128
#define NQ (NB * NN)        // 16384
#define NPAIR (NQ * KNBR)   // 131072

// ws layout. W planes in u16 units [0, 65536) == floats [0, 32768).
#define OFF16_W1H 0          // 16384 u16 (fragment order)
#define OFF16_W1L 16384
#define OFF16_W2H 32768
#define OFF16_W2L 49152
#define OFF_C0 32768         // float units
#define OFF_C1 32896
#define OFF_C2 33024
#define OFF_W0F 33152        // 384
#define OFF_Y 33792          // 2097152 floats
#define OFF_IDX (OFF_Y + NQ * DIMF)   // 131072 ints
#define OFF_PART (OFF_IDX + NPAIR)    // 16384*128*2 floats

typedef __attribute__((ext_vector_type(4))) float f32x4;
typedef __attribute__((ext_vector_type(8))) short short8v;

__device__ __forceinline__ float relu_f(float a) { return fmaxf(a, 0.0f); }

// fp32 -> bf16(hi, RNE) + bf16(lo, trunc of residual)
__device__ __forceinline__ void split3(float f, unsigned& hi, unsigned& lo) {
  const unsigned u = __float_as_uint(f);
  const unsigned h = (u + 0x7FFFu + ((u >> 16) & 1u)) >> 16;
  const float hf = __uint_as_float(h << 16);
  lo = __float_as_uint(f - hf) >> 16;
  hi = h;
}

__device__ __forceinline__ f32x4 mfma16x16x32bf(short8v a, short8v b, f32x4 c) {
  return __builtin_amdgcn_mfma_f32_16x16x32_bf16(a, b, c, 0, 0, 0);
}

// branchless sorted-8 insert; all indices compile-time (stays in registers)
__device__ __forceinline__ void knn_insert(float (&bd)[8], int (&bi)[8],
                                           float d, int mi) {
  const bool c = d < bd[7];
  bd[7] = c ? d : bd[7];
  bi[7] = c ? mi : bi[7];
#pragma unroll
  for (int k = 6; k >= 0; --k) {
    const bool cs = bd[k + 1] < bd[k];
    const float lo = cs ? bd[k + 1] : bd[k];
    const float hi = cs ? bd[k] : bd[k + 1];
    const int il = cs ? bi[k + 1] : bi[k];
    const int ih = cs ? bi[k] : bi[k + 1];
    bd[k] = lo; bd[k + 1] = hi;
    bi[k] = il; bi[k + 1] = ih;
  }
}

// ascending compare-swap of (d,i) pairs at compile-time slots a<b
#define PCSWAP(md, mi_, a, b)                        \
  {                                                  \
    const bool c_ = (md)[b] < (md)[a];               \
    const float lo_ = c_ ? (md)[b] : (md)[a];        \
    const float hi_ = c_ ? (md)[a] : (md)[b];        \
    const int il_ = c_ ? (mi_)[b] : (mi_)[a];        \
    const int ih_ = c_ ? (mi_)[a] : (mi_)[b];        \
    (md)[a] = lo_; (md)[b] = hi_;                    \
    (mi_)[a] = il_; (mi_)[b] = ih_;                  \
  }

// ------------------------------- prep --------------------------------------
// grid 64 x 256. Fragment-order W store:
//   (fo,k) -> tile=(fo>>4)*4+(k>>5), lane=((k>>3)&3)*16+(fo&15), e=k&7
__global__ __launch_bounds__(256) void prep_kernel(
    const float* __restrict__ w0, const float* __restrict__ b0,
    const float* __restrict__ wstk, const float* __restrict__ bstk,
    const float* __restrict__ g, const float* __restrict__ be,
    const float* __restrict__ bm, const float* __restrict__ bv,
    float* __restrict__ ws) {
  const int i = blockIdx.x * 256 + threadIdx.x;  // 16384
  unsigned short* __restrict__ wsh = (unsigned short*)ws;
  {
    const int fo = i >> 7, k = i & 127;
    const float s1 = g[128 + fo] / sqrtf(bv[128 + fo] + EPSF);
    const float s2 = g[256 + fo] / sqrtf(bv[256 + fo] + EPSF);
    unsigned h1, l1, h2, l2;
    split3(wstk[i] * s1, h1, l1);
    split3(wstk[16384 + i] * s2, h2, l2);
    const int dst = ((fo >> 4) * 4 + (k >> 5)) * 512 +
                    (((k >> 3) & 3) * 16 + (fo & 15)) * 8 + (k & 7);
    wsh[OFF16_W1H + dst] = (unsigned short)h1;
    wsh[OFF16_W1L + dst] = (unsigned short)l1;
    wsh[OFF16_W2H + dst] = (unsigned short)h2;
    wsh[OFF16_W2L + dst] = (unsigned short)l2;
  }
  if (blockIdx.x == 0 && threadIdx.x < 128) {
    const int fo = threadIdx.x;
    const float s0 = g[fo] / sqrtf(bv[fo] + EPSF);
    const float s1 = g[128 + fo] / sqrtf(bv[128 + fo] + EPSF);
    const float s2 = g[256 + fo] / sqrtf(bv[256 + fo] + EPSF);
    ws[OFF_C0 + fo] = (b0[fo] - bm[fo]) * s0 + be[fo];
    ws[OFF_C1 + fo] = (bstk[fo] - bm[128 + fo]) * s1 + be[128 + fo];
    ws[OFF_C2 + fo] = (bstk[128 + fo] - bm[256 + fo]) * s2 + be[256 + fo];
    ws[OFF_W0F + 3 * fo + 0] = w0[3 * fo + 0] * s0;
    ws[OFF_W0F + 3 * fo + 1] = w0[3 * fo + 1] * s0;
    ws[OFF_W0F + 3 * fo + 2] = w0[3 * fo + 2] * s0;
  }
}

// ------------------------------- ycomp -------------------------------------
__global__ __launch_bounds__(256) void y_kernel(const float* __restrict__ x,
                                                float* __restrict__ ws) {
  const int gid = blockIdx.x * 256 + threadIdx.x;  // 2,097,152
  const int q = gid >> 7, f = gid & 127;
  const int b = q >> 11, n = q & 2047;
  const float* __restrict__ W0f = ws + OFF_W0F;
  const float w0 = W0f[f * 3 + 0], w1 = W0f[f * 3 + 1], w2 = W0f[f * 3 + 2];
  const float x0 = x[b * 6144 + n];
  const float x1 = x[b * 6144 + 2048 + n];
  const float x2 = x[b * 6144 + 4096 + n];
  ws[OFF_Y + gid] = fmaf(w2, x2, fmaf(w1, x1, w0 * x0));
}

// ------------------------------- knn ---------------------------------------
// wg = qb*16 + r ; 256 threads = 256 queries; 128 candidates (range r).
// Dual even/odd top-8 chains for ILP; merged at end (ties between chains
// resolve to the even/earlier entry — differs from ref only on bit-equal
// distances at the 8/9 boundary, probability ~2^-24).
__global__ __launch_bounds__(256) void knn_part_kernel(
    const float* __restrict__ x, float* __restrict__ ws) {
  __shared__ float4 xs4[128];
  const int t = threadIdx.x;
  const int wg = blockIdx.x;  // 1024
  const int qb = wg >> 4, r = wg & 15;
  const int b = qb >> 3;
  const float* __restrict__ xb = x + b * 3 * NN;
  if (t < 128) {
    const int i = r * 128 + t;
    const float a0 = xb[i];
    const float a1 = xb[2048 + i];
    const float a2 = xb[4096 + i];
    const float sq = fmaf(a2, a2, fmaf(a1, a1, a0 * a0));
    xs4[t] = make_float4(a0, a1, a2, sq);
  }
  __syncthreads();
  const int n = (qb & 7) * 256 + t;
  const int q = b * NN + n;
  const float qx0 = xb[n], qx1 = xb[2048 + n], qx2 = xb[4096 + n];
  const float sqn = fmaf(qx2, qx2, fmaf(qx1, qx1, qx0 * qx0));

  float bdE[8], bdO[8];
  int biE[8], biO[8];
#pragma unroll
  for (int k = 0; k < 8; ++k) {
    bdE[k] = FMAXV; bdO[k] = FMAXV;
    biE[k] = 0; biO[k] = 0;
  }
  const int gbase = b * NN + r * 128;
#pragma unroll 4
  for (int mm = 0; mm < 128; mm += 2) {
    const float4 cE = xs4[mm];
    const float4 cO = xs4[mm + 1];
    const float innerE = fmaf(qx2, cE.z, fmaf(qx1, cE.y, qx0 * cE.x));
    const float innerO = fmaf(qx2, cO.z, fmaf(qx1, cO.y, qx0 * cO.x));
    const float dE = (sqn - 2.0f * innerE) + cE.w;
    const float dO = (sqn - 2.0f * innerO) + cO.w;
    knn_insert(bdE, biE, dE, gbase + mm);
    knn_insert(bdO, biO, dO, gbase + mm + 1);
  }
  // fold odd list into even list
#pragma unroll
  for (int k = 0; k < 8; ++k) knn_insert(bdE, biE, bdO[k], biO[k]);

  float2* __restrict__ part = (float2*)(ws + OFF_PART);
  const int eb = r * 8;
#pragma unroll
  for (int k = 0; k < 8; ++k)
    part[(long)(eb + k) * NQ + q] = make_float2(bdE[k], __int_as_float(biE[k]));
}

// 4 lanes per query: each merges 32 partial entries (independent chains),
// then 2 rounds of shfl_xor Batcher merge (min vs reversed partner + 3-stage
// bitonic cleanup). 256 WGs x 256 thr = 1024 waves.
__global__ __launch_bounds__(256) void knn_merge_kernel(float* __restrict__ ws) {
  const int t = threadIdx.x;
  const int q = blockIdx.x * 64 + (t >> 2);
  const int s = t & 3;
  const float2* __restrict__ part = (const float2*)(ws + OFF_PART);

  float bd[8]; int bi[8];
#pragma unroll
  for (int k = 0; k < 8; ++k) { bd[k] = FMAXV; bi[k] = 0; }
#pragma unroll 4
  for (int j = 0; j < 32; ++j) {
    const float2 en = part[(long)(s * 32 + j) * NQ + q];
    knn_insert(bd, bi, en.x, __float_as_int(en.y));
  }

#pragma unroll
  for (int rnd = 0; rnd < 2; ++rnd) {
    const int m = 1 << rnd;
    float pd[8]; int pi[8];
#pragma unroll
    for (int k = 0; k < 8; ++k) {
      pd[k] = __shfl_xor(bd[k], m, 64);
      pi[k] = __shfl_xor(bi[k], m, 64);
    }
    float md[8]; int mi_[8];
#pragma unroll
    for (int k = 0; k < 8; ++k) {  // low-8 of union (bitonic result)
      const bool c = pd[7 - k] < bd[k];
      md[k] = c ? pd[7 - k] : bd[k];
      mi_[k] = c ? pi[7 - k] : bi[k];
    }
    // 3-stage bitonic cleanup (strides 4,2,1)
    PCSWAP(md, mi_, 0, 4) PCSWAP(md, mi_, 1, 5)
    PCSWAP(md, mi_, 2, 6) PCSWAP(md, mi_, 3, 7)
    PCSWAP(md, mi_, 0, 2) PCSWAP(md, mi_, 1, 3)
    PCSWAP(md, mi_, 4, 6) PCSWAP(md, mi_, 5, 7)
    PCSWAP(md, mi_, 0, 1) PCSWAP(md, mi_, 2, 3)
    PCSWAP(md, mi_, 4, 5) PCSWAP(md, mi_, 6, 7)
#pragma unroll
    for (int k = 0; k < 8; ++k) { bd[k] = md[k]; bi[k] = mi_[k]; }
  }

  if (s == 0) {
    int* __restrict__ idxg = (int*)(ws + OFF_IDX);
    int* o = idxg + q * 8;
#pragma unroll
    for (int k = 0; k < 8; ++k) o[k] = bi[k];
  }
}

// --------------------------- persistent fused ------------------------------
// 256 blocks x 512 thr (8 waves: wr=w>>2 pair-half, wc=w&3 fo-slice).
// Block bid: batch bb=bid&7, queries qseg*64..+64 (qseg=bid>>3), 8 chunks of
// 64 pairs. LDS 128KB: A dbuf 2x32KB @0, H 32KB @64K, OS 32KB @96K.
// A-plane 16B chunks swizzled col = kc ^ (row&7); H 16B chunks cc ^= (p&7).
__global__ __launch_bounds__(512, 2) void fused_kernel(float* __restrict__ ws,
                                                       float* __restrict__ out) {
  extern __shared__ char smem[];
  unsigned* __restrict__ H = (unsigned*)(smem + 65536);
  float* __restrict__ OS = (float*)(smem + 98304);

  const float* __restrict__ y = ws + OFF_Y;
  const int* __restrict__ idxg = (const int*)(ws + OFF_IDX);
  const unsigned short* __restrict__ wsu = (const unsigned short*)ws;

  const int t = threadIdx.x;
  const int lane = t & 63, w = t >> 6;
  const int wr = w >> 2, wc = w & 3;
  const int bid = blockIdx.x;
  const int bb = bid & 7, qseg = bid >> 3;
  const int chunk0 = bb * 256 + qseg * 8;

  // ---- W fragments -> registers (once; coalesced 1KB/wave frag loads) ----
  short8v w1h[2][4], w1l[2][4], w2h[2][4], w2l[2][4];
#pragma unroll
  for (int ft = 0; ft < 2; ++ft)
#pragma unroll
    for (int ks = 0; ks < 4; ++ks) {
      const int off = ((wc * 2 + ft) * 4 + ks) * 512 + lane * 8;
      w1h[ft][ks] = *(const short8v*)(wsu + OFF16_W1H + off);
      w1l[ft][ks] = *(const short8v*)(wsu + OFF16_W1L + off);
      w2h[ft][ks] = *(const short8v*)(wsu + OFF16_W2H + off);
      w2l[ft][ks] = *(const short8v*)(wsu + OFF16_W2L + off);
    }

  const float c1v0 = (ws + OFF_C1)[wc * 32 + (lane & 15)];
  const float c1v1 = (ws + OFF_C1)[wc * 32 + 16 + (lane & 15)];
  const float c2v0 = (ws + OFF_C2)[wc * 32 + (lane & 15)];
  const float c2v1 = (ws + OFF_C2)[wc * 32 + 16 + (lane & 15)];

  // ---- per-thread A-staging constants ----
  const int row = t >> 3, part8 = t & 7;
  const float* __restrict__ c0p = ws + OFF_C0 + part8 * 16;
  const float4 c0a = *(const float4*)(c0p + 0);
  const float4 c0b = *(const float4*)(c0p + 4);
  const float4 c0c = *(const float4*)(c0p + 8);
  const float4 c0d = *(const float4*)(c0p + 12);

// pack 8 floats (relu'd h1 values) into hi/lo int4 and write swizzled
#define PACK_WRITE_A(base, hv, kc)                              \
  {                                                             \
    unsigned hh[8], ll[8];                                      \
    _Pragma("unroll") for (int e = 0; e < 8; ++e)               \
        split3(hv[e], hh[e], ll[e]);                            \
    int4 hp, lp;                                                \
    hp.x = (int)(hh[0] | (hh[1] << 16));                        \
    hp.y = (int)(hh[2] | (hh[3] << 16));                        \
    hp.z = (int)(hh[4] | (hh[5] << 16));                        \
    hp.w = (int)(hh[6] | (hh[7] << 16));                        \
    lp.x = (int)(ll[0] | (ll[1] << 16));                        \
    lp.y = (int)(ll[2] | (ll[3] << 16));                        \
    lp.z = (int)(ll[4] | (ll[5] << 16));                        \
    lp.w = (int)(ll[6] | (ll[7] << 16));                        \
    const int col = (kc) ^ (row & 7);                           \
    *(int4*)((base) + row * 256 + col * 16) = hp;               \
    *(int4*)((base) + 16384 + row * 256 + col * 16) = lp;       \
  }

  // ---- prologue: stage A[0] into buf0 ----
  {
    const int gp = chunk0 * 64 + row;
    const int mg = idxg[gp];
    const float* __restrict__ ym = y + (long)mg * 128 + part8 * 16;
    const float* __restrict__ yn = y + (long)(gp >> 3) * 128 + part8 * 16;
    const float4 a0 = *(const float4*)(ym + 0);
    const float4 a1 = *(const float4*)(ym + 4);
    const float4 a2 = *(const float4*)(ym + 8);
    const float4 a3 = *(const float4*)(ym + 12);
    const float4 n0 = *(const float4*)(yn + 0);
    const float4 n1 = *(const float4*)(yn + 4);
    const float4 n2 = *(const float4*)(yn + 8);
    const float4 n3 = *(const float4*)(yn + 12);
    float hv0[8] = {relu_f(a0.x - n0.x + c0a.x), relu_f(a0.y - n0.y + c0a.y),
                    relu_f(a0.z - n0.z + c0a.z), relu_f(a0.w - n0.w + c0a.w),
                    relu_f(a1.x - n1.x + c0b.x), relu_f(a1.y - n1.y + c0b.y),
                    relu_f(a1.z - n1.z + c0b.z), relu_f(a1.w - n1.w + c0b.w)};
    float hv1[8] = {relu_f(a2.x - n2.x + c0c.x), relu_f(a2.y - n2.y + c0c.y),
                    relu_f(a2.z - n2.z + c0c.z), relu_f(a2.w - n2.w + c0c.w),
                    relu_f(a3.x - n3.x + c0d.x), relu_f(a3.y - n3.y + c0d.y),
                    relu_f(a3.z - n3.z + c0d.z), relu_f(a3.w - n3.w + c0d.w)};
    PACK_WRITE_A(smem, hv0, part8 * 2)
    PACK_WRITE_A(smem, hv1, part8 * 2 + 1)
  }
  __syncthreads();

#pragma unroll 1
  for (int j = 0; j < 8; ++j) {
    char* __restrict__ Acur = smem + (j & 1) * 32768;
    char* __restrict__ Anxt = smem + ((j & 1) ^ 1) * 32768;

    // issue next chunk's idx early (independent of g1)
    int mg_next = 0, gp_next = 0;
    if (j < 7) {
      gp_next = (chunk0 + j + 1) * 64 + row;
      mg_next = idxg[gp_next];
    }

    // ---- g1: acc = h1 . W1^T (bf16x3), A from Acur ----
    f32x4 acc[2][2];
#pragma unroll
    for (int pt = 0; pt < 2; ++pt)
#pragma unroll
      for (int ft = 0; ft < 2; ++ft) acc[pt][ft] = (f32x4){0.f, 0.f, 0.f, 0.f};
#pragma unroll
    for (int ks = 0; ks < 4; ++ks) {
      const int kc = ks * 4 + (lane >> 4);
#pragma unroll
      for (int pt = 0; pt < 2; ++pt) {
        const int arow = wr * 32 + pt * 16 + (lane & 15);
        const int col = kc ^ (arow & 7);
        const short8v ah = *(const short8v*)(Acur + arow * 256 + col * 16);
        const short8v al =
            *(const short8v*)(Acur + 16384 + arow * 256 + col * 16);
#pragma unroll
        for (int ft = 0; ft < 2; ++ft) {
          acc[pt][ft] = mfma16x16x32bf(al, w1h[ft][ks], acc[pt][ft]);
          acc[pt][ft] = mfma16x16x32bf(ah, w1l[ft][ks], acc[pt][ft]);
          acc[pt][ft] = mfma16x16x32bf(ah, w1h[ft][ks], acc[pt][ft]);
        }
      }
    }

    // ---- issue next chunk's y loads (latency hides under H + g2) ----
    float4 a0, a1, a2, a3, n0, n1, n2, n3;
    if (j < 7) {
      const float* __restrict__ ym = y + (long)mg_next * 128 + part8 * 16;
      const float* __restrict__ yn = y + (long)(gp_next >> 3) * 128 + part8 * 16;
      a0 = *(const float4*)(ym + 0);
      a1 = *(const float4*)(ym + 4);
      a2 = *(const float4*)(ym + 8);
      a3 = *(const float4*)(ym + 12);
      n0 = *(const float4*)(yn + 0);
      n1 = *(const float4*)(yn + 4);
      n2 = *(const float4*)(yn + 8);
      n3 = *(const float4*)(yn + 12);
    }

    // ---- g1 epilogue: relu(acc+c1) -> H (packed u32, swizzled) ----
#pragma unroll
    for (int pt = 0; pt < 2; ++pt)
#pragma unroll
      for (int ft = 0; ft < 2; ++ft) {
        const int fo = wc * 32 + ft * 16 + (lane & 15);
        const int cc = fo >> 2;
        const float cb = ft ? c1v1 : c1v0;
#pragma unroll
        for (int reg = 0; reg < 4; ++reg) {
          const int p = wr * 32 + pt * 16 + (lane >> 4) * 4 + reg;
          const float vv = relu_f(acc[pt][ft][reg] + cb);
          unsigned hh, ll;
          split3(vv, hh, ll);
          H[p * 128 + ((cc ^ (p & 7)) << 2) + (fo & 3)] = (hh << 16) | ll;
        }
      }
    __syncthreads();  // H ready

    // ---- g2: acc2 = h2 . W2^T (bf16x3), A from H ----
    f32x4 acc2[2][2];
#pragma unroll
    for (int pt = 0; pt < 2; ++pt)
#pragma unroll
      for (int ft = 0; ft < 2; ++ft) acc2[pt][ft] = (f32x4){0.f, 0.f, 0.f, 0.f};
#pragma unroll
    for (int ks = 0; ks < 4; ++ks) {
      const int cc0 = ks * 8 + (lane >> 4) * 2;
#pragma unroll
      for (int pt = 0; pt < 2; ++pt) {
        const int p = wr * 32 + pt * 16 + (lane & 15);
        const int4 u0 = *(const int4*)&H[p * 128 + ((cc0 ^ (p & 7)) << 2)];
        const int4 u1 = *(const int4*)&H[p * 128 + (((cc0 + 1) ^ (p & 7)) << 2)];
        const unsigned uu[8] = {(unsigned)u0.x, (unsigned)u0.y, (unsigned)u0.z,
                                (unsigned)u0.w, (unsigned)u1.x, (unsigned)u1.y,
                                (unsigned)u1.z, (unsigned)u1.w};
        short8v ah, al;
#pragma unroll
        for (int e = 0; e < 8; ++e) {
          ah[e] = (short)(uu[e] >> 16);
          al[e] = (short)(uu[e] & 0xFFFFu);
        }
#pragma unroll
        for (int ft = 0; ft < 2; ++ft) {
          acc2[pt][ft] = mfma16x16x32bf(al, w2h[ft][ks], acc2[pt][ft]);
          acc2[pt][ft] = mfma16x16x32bf(ah, w2l[ft][ks], acc2[pt][ft]);
          acc2[pt][ft] = mfma16x16x32bf(ah, w2h[ft][ks], acc2[pt][ft]);
        }
      }
    }
    __syncthreads();  // H reads done (next iter may overwrite H)

    // ---- g2 epilogue: relu+max over 8 pairs/query -> OS rows j*8.. ----
    {
      const int g = lane >> 4;
#pragma unroll
      for (int pt = 0; pt < 2; ++pt)
#pragma unroll
        for (int ft = 0; ft < 2; ++ft) {
          const int fo = wc * 32 + ft * 16 + (lane & 15);
          const float cb = ft ? c2v1 : c2v0;
          const float v0 = relu_f(acc2[pt][ft][0] + cb);
          const float v1 = relu_f(acc2[pt][ft][1] + cb);
          const float v2 = relu_f(acc2[pt][ft][2] + cb);
          const float v3 = relu_f(acc2[pt][ft][3] + cb);
          float m = fmaxf(fmaxf(v0, v1), fmaxf(v2, v3));
          m = fmaxf(m, __shfl_xor(m, 16, 64));
          if ((g & 1) == 0) {
            const int qloc = wr * 4 + pt * 2 + (g >> 1);
            OS[(j * 8 + qloc) * 128 + fo] = m;
          }
        }
    }

    // ---- pack & write A[j+1] into Anxt (loads returned during g2) ----
    if (j < 7) {
      float hv0[8] = {relu_f(a0.x - n0.x + c0a.x), relu_f(a0.y - n0.y + c0a.y),
                      relu_f(a0.z - n0.z + c0a.z), relu_f(a0.w - n0.w + c0a.w),
                      relu_f(a1.x - n1.x + c0b.x), relu_f(a1.y - n1.y + c0b.y),
                      relu_f(a1.z - n1.z + c0b.z), relu_f(a1.w - n1.w + c0b.w)};
      float hv1[8] = {relu_f(a2.x - n2.x + c0c.x), relu_f(a2.y - n2.y + c0c.y),
                      relu_f(a2.z - n2.z + c0c.z), relu_f(a2.w - n2.w + c0c.w),
                      relu_f(a3.x - n3.x + c0d.x), relu_f(a3.y - n3.y + c0d.y),
                      relu_f(a3.z - n3.z + c0d.z), relu_f(a3.w - n3.w + c0d.w)};
      PACK_WRITE_A(Anxt, hv0, part8 * 2)
      PACK_WRITE_A(Anxt, hv1, part8 * 2 + 1)
    }
    __syncthreads();  // A[j+1] ready; OS rows settled
  }

  // ---- final coalesced out-write: OS[64][128] -> out[bb][f][qseg*64..] ----
  {
    const int f = t >> 2, seg = t & 3;
    float* __restrict__ op = out + (long)(bb * 128 + f) * 2048 + qseg * 64 + seg * 16;
#pragma unroll
    for (int u = 0; u < 4; ++u) {
      float4 o;
      o.x = OS[(seg * 16 + u * 4 + 0) * 128 + f];
      o.y = OS[(seg * 16 + u * 4 + 1) * 128 + f];
      o.z = OS[(seg * 16 + u * 4 + 2) * 128 + f];
      o.w = OS[(seg * 16 + u * 4 + 3) * 128 + f];
      *(float4*)(op + u * 4) = o;
    }
  }
}

// ------------------------------- launch ------------------------------------
extern "C" void kernel_launch(void* const* d_in, const int* in_sizes, int n_in,
                              void* d_out, int out_size, void* d_ws,
                              size_t ws_size, hipStream_t stream) {
  (void)in_sizes; (void)n_in; (void)out_size; (void)ws_size;
  const float* x = (const float*)d_in[0];
  const float* w0 = (const float*)d_in[1];
  const float* b0 = (const float*)d_in[2];
  const float* wst = (const float*)d_in[3];
  const float* bst = (const float*)d_in[4];
  const float* g = (const float*)d_in[5];
  const float* be = (const float*)d_in[6];
  const float* bm = (const float*)d_in[7];
  const float* bv = (const float*)d_in[8];
  float* out = (float*)d_out;
  float* ws = (float*)d_ws;

  hipFuncSetAttribute((const void*)fused_kernel,
                      hipFuncAttributeMaxDynamicSharedMemorySize, 131072);

  prep_kernel<<<64, 256, 0, stream>>>(w0, b0, wst, bst, g, be, bm, bv, ws);
  y_kernel<<<NQ * DIMF / 256, 256, 0, stream>>>(x, ws);
  knn_part_kernel<<<1024, 256, 0, stream>>>(x, ws);
  knn_merge_kernel<<<NQ / 64, 256, 0, stream>>>(ws);
  fused_kernel<<<256, 512, 131072, stream>>>(ws, out);
}

// Round 8
// 100.768 us; speedup vs baseline: 2.4284x; 2.4284x over previous
//
#include <hip/hip_runtime.h>

// ---------------------------------------------------------------------------
// FeatureNet: kNN(K=8) relative grouping -> [conv1x1+BN+ReLU] x3 -> max over K
// B=8, N=2048, DIM=128, fp32 in/out.
//
// prep     : fold BN; W1/W2 stored as 4 bf16 planes in MFMA FRAGMENT ORDER
// y        : y[q][f] = W0f . x[q]
// knn_part : 16 ranges x 128 cands; keys-only top-8 (dual chain) -> threshold
//            -> collect pass emits unsorted top-8 set. NAMED SCALARS ONLY
//            (R7 lesson: array-state top-k code -> 5x VALU explosion).
// knn_merge: 4 lanes/query, 32 entries each, shfl_xor bitonic merge (scalars)
// fused    : PERSISTENT: 256 blocks (1/CU), 8 chunks each, W in 128 VGPRs.
//            A double-buffered LDS, H own region, OS written coalesced at end.
//            XCD-aligned: block bid -> batch bid&7 (1MB y slice per XCD L2).
// ---------------------------------------------------------------------------

#define EPSF 1e-5f
#define FMAXV 3.402823466e+38f

#define NB 8
#define NN 2048
#define KNBR 8
#define DIMF 128
#define NQ (NB * NN)        // 16384
#define NPAIR (NQ * KNBR)   // 131072

// ws layout. W planes in u16 units [0, 65536) == floats [0, 32768).
#define OFF16_W1H 0          // 16384 u16 (fragment order)
#define OFF16_W1L 16384
#define OFF16_W2H 32768
#define OFF16_W2L 49152
#define OFF_C0 32768         // float units
#define OFF_C1 32896
#define OFF_C2 33024
#define OFF_W0F 33152        // 384
#define OFF_Y 33792          // 2097152 floats
#define OFF_IDX (OFF_Y + NQ * DIMF)   // 131072 ints
#define OFF_PART (OFF_IDX + NPAIR)    // 16384*128*2 floats

typedef __attribute__((ext_vector_type(4))) float f32x4;
typedef __attribute__((ext_vector_type(8))) short short8v;

__device__ __forceinline__ float relu_f(float a) { return fmaxf(a, 0.0f); }

// fp32 -> bf16(hi, RNE) + bf16(lo, trunc of residual)
__device__ __forceinline__ void split3(float f, unsigned& hi, unsigned& lo) {
  const unsigned u = __float_as_uint(f);
  const unsigned h = (u + 0x7FFFu + ((u >> 16) & 1u)) >> 16;
  const float hf = __uint_as_float(h << 16);
  lo = __float_as_uint(f - hf) >> 16;
  hi = h;
}

__device__ __forceinline__ f32x4 mfma16x16x32bf(short8v a, short8v b, f32x4 c) {
  return __builtin_amdgcn_mfma_f32_16x16x32_bf16(a, b, c, 0, 0, 0);
}

// ---- named-scalar selection primitives (NO arrays — see R7 post-mortem) ----
#define KNN_CSWAP(da, db, ia, ib)            \
  {                                          \
    const bool c_ = (db) < (da);             \
    const float lo_ = c_ ? (db) : (da);      \
    const float hi_ = c_ ? (da) : (db);      \
    const int il_ = c_ ? (ib) : (ia);        \
    const int ih_ = c_ ? (ia) : (ib);        \
    (da) = lo_; (db) = hi_;                  \
    (ia) = il_; (ib) = ih_;                  \
  }

#define KNN_INSERT_BL(d, mi)                  \
  {                                           \
    const bool cc_ = (d) < b7v;               \
    b7v = cc_ ? (d) : b7v;                    \
    i7v = cc_ ? (mi) : i7v;                   \
    KNN_CSWAP(b6v, b7v, i6v, i7v)             \
    KNN_CSWAP(b5v, b6v, i5v, i6v)             \
    KNN_CSWAP(b4v, b5v, i4v, i5v)             \
    KNN_CSWAP(b3v, b4v, i3v, i4v)             \
    KNN_CSWAP(b2v, b3v, i2v, i3v)             \
    KNN_CSWAP(b1v, b2v, i1v, i2v)             \
    KNN_CSWAP(b0v, b1v, i0v, i1v)             \
  }

// keys-only sorted-8 insert (ascending), 16 ops
#define KINS8(K0, K1, K2, K3, K4, K5, K6, K7, dv)     \
  {                                                   \
    float t_ = (dv), n_;                              \
    n_ = fminf(K0, t_); t_ = fmaxf(K0, t_); K0 = n_;  \
    n_ = fminf(K1, t_); t_ = fmaxf(K1, t_); K1 = n_;  \
    n_ = fminf(K2, t_); t_ = fmaxf(K2, t_); K2 = n_;  \
    n_ = fminf(K3, t_); t_ = fmaxf(K3, t_); K3 = n_;  \
    n_ = fminf(K4, t_); t_ = fmaxf(K4, t_); K4 = n_;  \
    n_ = fminf(K5, t_); t_ = fmaxf(K5, t_); K5 = n_;  \
    n_ = fminf(K6, t_); t_ = fmaxf(K6, t_); K6 = n_;  \
    n_ = fminf(K7, t_); t_ = fmaxf(K7, t_); K7 = n_;  \
  }

#define SELMIN(nd, ni, bd, bi, pd, pi)   \
  {                                      \
    const bool c_ = (pd) < (bd);         \
    nd = c_ ? (pd) : (bd);               \
    ni = c_ ? (pi) : (bi);               \
  }

// merge own sorted-8 (b0v..b7v/i0v..i7v) with xor-partner's; keep low 8 sorted
#define MERGE_ROUND(mm_)                                           \
  {                                                                \
    const float pd0 = __shfl_xor(b0v, mm_, 64);                    \
    const float pd1 = __shfl_xor(b1v, mm_, 64);                    \
    const float pd2 = __shfl_xor(b2v, mm_, 64);                    \
    const float pd3 = __shfl_xor(b3v, mm_, 64);                    \
    const float pd4 = __shfl_xor(b4v, mm_, 64);                    \
    const float pd5 = __shfl_xor(b5v, mm_, 64);                    \
    const float pd6 = __shfl_xor(b6v, mm_, 64);                    \
    const float pd7 = __shfl_xor(b7v, mm_, 64);                    \
    const int pi0 = __shfl_xor(i0v, mm_, 64);                      \
    const int pi1 = __shfl_xor(i1v, mm_, 64);                      \
    const int pi2 = __shfl_xor(i2v, mm_, 64);                      \
    const int pi3 = __shfl_xor(i3v, mm_, 64);                      \
    const int pi4 = __shfl_xor(i4v, mm_, 64);                      \
    const int pi5 = __shfl_xor(i5v, mm_, 64);                      \
    const int pi6 = __shfl_xor(i6v, mm_, 64);                      \
    const int pi7 = __shfl_xor(i7v, mm_, 64);                      \
    float nd0, nd1, nd2, nd3, nd4, nd5, nd6, nd7;                  \
    int ni0, ni1, ni2, ni3, ni4, ni5, ni6, ni7;                    \
    SELMIN(nd0, ni0, b0v, i0v, pd7, pi7)                           \
    SELMIN(nd1, ni1, b1v, i1v, pd6, pi6)                           \
    SELMIN(nd2, ni2, b2v, i2v, pd5, pi5)                           \
    SELMIN(nd3, ni3, b3v, i3v, pd4, pi4)                           \
    SELMIN(nd4, ni4, b4v, i4v, pd3, pi3)                           \
    SELMIN(nd5, ni5, b5v, i5v, pd2, pi2)                           \
    SELMIN(nd6, ni6, b6v, i6v, pd1, pi1)                           \
    SELMIN(nd7, ni7, b7v, i7v, pd0, pi0)                           \
    KNN_CSWAP(nd0, nd4, ni0, ni4) KNN_CSWAP(nd1, nd5, ni1, ni5)    \
    KNN_CSWAP(nd2, nd6, ni2, ni6) KNN_CSWAP(nd3, nd7, ni3, ni7)    \
    KNN_CSWAP(nd0, nd2, ni0, ni2) KNN_CSWAP(nd1, nd3, ni1, ni3)    \
    KNN_CSWAP(nd4, nd6, ni4, ni6) KNN_CSWAP(nd5, nd7, ni5, ni7)    \
    KNN_CSWAP(nd0, nd1, ni0, ni1) KNN_CSWAP(nd2, nd3, ni2, ni3)    \
    KNN_CSWAP(nd4, nd5, ni4, ni5) KNN_CSWAP(nd6, nd7, ni6, ni7)    \
    b0v = nd0; b1v = nd1; b2v = nd2; b3v = nd3;                    \
    b4v = nd4; b5v = nd5; b6v = nd6; b7v = nd7;                    \
    i0v = ni0; i1v = ni1; i2v = ni2; i3v = ni3;                    \
    i4v = ni4; i5v = ni5; i6v = ni6; i7v = ni7;                    \
  }

// ------------------------------- prep --------------------------------------
// grid 64 x 256. Fragment-order W store:
//   (fo,k) -> tile=(fo>>4)*4+(k>>5), lane=((k>>3)&3)*16+(fo&15), e=k&7
__global__ __launch_bounds__(256) void prep_kernel(
    const float* __restrict__ w0, const float* __restrict__ b0,
    const float* __restrict__ wstk, const float* __restrict__ bstk,
    const float* __restrict__ g, const float* __restrict__ be,
    const float* __restrict__ bm, const float* __restrict__ bv,
    float* __restrict__ ws) {
  const int i = blockIdx.x * 256 + threadIdx.x;  // 16384
  unsigned short* __restrict__ wsh = (unsigned short*)ws;
  {
    const int fo = i >> 7, k = i & 127;
    const float s1 = g[128 + fo] / sqrtf(bv[128 + fo] + EPSF);
    const float s2 = g[256 + fo] / sqrtf(bv[256 + fo] + EPSF);
    unsigned h1, l1, h2, l2;
    split3(wstk[i] * s1, h1, l1);
    split3(wstk[16384 + i] * s2, h2, l2);
    const int dst = ((fo >> 4) * 4 + (k >> 5)) * 512 +
                    (((k >> 3) & 3) * 16 + (fo & 15)) * 8 + (k & 7);
    wsh[OFF16_W1H + dst] = (unsigned short)h1;
    wsh[OFF16_W1L + dst] = (unsigned short)l1;
    wsh[OFF16_W2H + dst] = (unsigned short)h2;
    wsh[OFF16_W2L + dst] = (unsigned short)l2;
  }
  if (blockIdx.x == 0 && threadIdx.x < 128) {
    const int fo = threadIdx.x;
    const float s0 = g[fo] / sqrtf(bv[fo] + EPSF);
    const float s1 = g[128 + fo] / sqrtf(bv[128 + fo] + EPSF);
    const float s2 = g[256 + fo] / sqrtf(bv[256 + fo] + EPSF);
    ws[OFF_C0 + fo] = (b0[fo] - bm[fo]) * s0 + be[fo];
    ws[OFF_C1 + fo] = (bstk[fo] - bm[128 + fo]) * s1 + be[128 + fo];
    ws[OFF_C2 + fo] = (bstk[128 + fo] - bm[256 + fo]) * s2 + be[256 + fo];
    ws[OFF_W0F + 3 * fo + 0] = w0[3 * fo + 0] * s0;
    ws[OFF_W0F + 3 * fo + 1] = w0[3 * fo + 1] * s0;
    ws[OFF_W0F + 3 * fo + 2] = w0[3 * fo + 2] * s0;
  }
}

// ------------------------------- ycomp -------------------------------------
__global__ __launch_bounds__(256) void y_kernel(const float* __restrict__ x,
                                                float* __restrict__ ws) {
  const int gid = blockIdx.x * 256 + threadIdx.x;  // 2,097,152
  const int q = gid >> 7, f = gid & 127;
  const int b = q >> 11, n = q & 2047;
  const float* __restrict__ W0f = ws + OFF_W0F;
  const float w0 = W0f[f * 3 + 0], w1 = W0f[f * 3 + 1], w2 = W0f[f * 3 + 2];
  const float x0 = x[b * 6144 + n];
  const float x1 = x[b * 6144 + 2048 + n];
  const float x2 = x[b * 6144 + 4096 + n];
  ws[OFF_Y + gid] = fmaf(w2, x2, fmaf(w1, x1, w0 * x0));
}

// ------------------------------- knn ---------------------------------------
// wg = qb*16 + r ; 256 threads = 256 queries; 128 candidates (range r).
// Phase 1: keys-only dual-chain top-8 -> exact 8th-smallest threshold.
// Phase 2: rescan (bitwise-identical d), emit first 8 with d <= thr
//          (index order == jax top_k lowest-index tie set). Output UNSORTED
//          (downstream is max over K — order-free).
__global__ __launch_bounds__(256) void knn_part_kernel(
    const float* __restrict__ x, float* __restrict__ ws) {
  __shared__ float4 xs4[128];
  const int t = threadIdx.x;
  const int wg = blockIdx.x;  // 1024
  const int qb = wg >> 4, r = wg & 15;
  const int b = qb >> 3;
  const float* __restrict__ xb = x + b * 3 * NN;
  if (t < 128) {
    const int i = r * 128 + t;
    const float a0 = xb[i];
    const float a1 = xb[2048 + i];
    const float a2 = xb[4096 + i];
    const float sq = fmaf(a2, a2, fmaf(a1, a1, a0 * a0));
    xs4[t] = make_float4(a0, a1, a2, sq);
  }
  __syncthreads();
  const int n = (qb & 7) * 256 + t;
  const int q = b * NN + n;
  const float qx0 = xb[n], qx1 = xb[2048 + n], qx2 = xb[4096 + n];
  const float sqn = fmaf(qx2, qx2, fmaf(qx1, qx1, qx0 * qx0));

  // ---- phase 1: keys-only, even/odd chains ----
  float e0 = FMAXV, e1 = FMAXV, e2 = FMAXV, e3 = FMAXV,
        e4 = FMAXV, e5 = FMAXV, e6 = FMAXV, e7 = FMAXV;
  float o0 = FMAXV, o1 = FMAXV, o2 = FMAXV, o3 = FMAXV,
        o4 = FMAXV, o5 = FMAXV, o6 = FMAXV, o7 = FMAXV;
#pragma unroll 4
  for (int mm = 0; mm < 128; mm += 2) {
    const float4 cE = xs4[mm];
    const float4 cO = xs4[mm + 1];
    const float innerE = fmaf(qx2, cE.z, fmaf(qx1, cE.y, qx0 * cE.x));
    const float innerO = fmaf(qx2, cO.z, fmaf(qx1, cO.y, qx0 * cO.x));
    const float dE = (sqn - 2.0f * innerE) + cE.w;
    const float dO = (sqn - 2.0f * innerO) + cO.w;
    KINS8(e0, e1, e2, e3, e4, e5, e6, e7, dE)
    KINS8(o0, o1, o2, o3, o4, o5, o6, o7, dO)
  }
  // 8th-smallest of union of two sorted-8 lists = max_k min(e_k, o_{7-k})
  const float u0 = fminf(e0, o7), u1 = fminf(e1, o6);
  const float u2 = fminf(e2, o5), u3 = fminf(e3, o4);
  const float u4 = fminf(e4, o3), u5 = fminf(e5, o2);
  const float u6 = fminf(e6, o1), u7 = fminf(e7, o0);
  const float thr = fmaxf(fmaxf(fmaxf(u0, u1), fmaxf(u2, u3)),
                          fmaxf(fmaxf(u4, u5), fmaxf(u6, u7)));

  // ---- phase 2: collect the set (identical d expression) ----
  float2* __restrict__ part = (float2*)(ws + OFF_PART);
  const int eb = r * 8;
  const int gbase = b * NN + r * 128;
  int cnt = 0;
#pragma unroll 4
  for (int mm = 0; mm < 128; ++mm) {
    const float4 c = xs4[mm];
    const float inner = fmaf(qx2, c.z, fmaf(qx1, c.y, qx0 * c.x));
    const float d = (sqn - 2.0f * inner) + c.w;
    if (d <= thr && cnt < 8) {
      part[(long)(eb + cnt) * NQ + q] =
          make_float2(d, __int_as_float(gbase + mm));
      ++cnt;
    }
  }
}

// 4 lanes per query: each keeps sorted top-8 of its 32 entries (named-scalar
// insert), then 2 shfl_xor Batcher merge rounds; lane s==0 writes indices.
__global__ __launch_bounds__(256) void knn_merge_kernel(float* __restrict__ ws) {
  const int t = threadIdx.x;
  const int q = blockIdx.x * 64 + (t >> 2);
  const int s = t & 3;
  const float2* __restrict__ part = (const float2*)(ws + OFF_PART);

  float b0v = FMAXV, b1v = FMAXV, b2v = FMAXV, b3v = FMAXV,
        b4v = FMAXV, b5v = FMAXV, b6v = FMAXV, b7v = FMAXV;
  int i0v = 0, i1v = 0, i2v = 0, i3v = 0, i4v = 0, i5v = 0, i6v = 0, i7v = 0;
#pragma unroll 4
  for (int j = 0; j < 32; ++j) {
    const float2 en = part[(long)(s * 32 + j) * NQ + q];
    const float d = en.x;
    const int mi = __float_as_int(en.y);
    KNN_INSERT_BL(d, mi)
  }
  MERGE_ROUND(1)
  MERGE_ROUND(2)
  if (s == 0) {
    int* __restrict__ idxg = (int*)(ws + OFF_IDX);
    int* o = idxg + q * 8;
    o[0] = i0v; o[1] = i1v; o[2] = i2v; o[3] = i3v;
    o[4] = i4v; o[5] = i5v; o[6] = i6v; o[7] = i7v;
  }
}

// --------------------------- persistent fused ------------------------------
// 256 blocks x 512 thr (8 waves: wr=w>>2 pair-half, wc=w&3 fo-slice).
// Block bid: batch bb=bid&7, queries qseg*64..+64 (qseg=bid>>3), 8 chunks of
// 64 pairs. LDS 128KB: A dbuf 2x32KB @0, H 32KB @64K, OS 32KB @96K.
// A-plane 16B chunks swizzled col = kc ^ (row&7); H 16B chunks cc ^= (p&7).
__global__ __launch_bounds__(512, 2) void fused_kernel(float* __restrict__ ws,
                                                       float* __restrict__ out) {
  extern __shared__ char smem[];
  unsigned* __restrict__ H = (unsigned*)(smem + 65536);
  float* __restrict__ OS = (float*)(smem + 98304);

  const float* __restrict__ y = ws + OFF_Y;
  const int* __restrict__ idxg = (const int*)(ws + OFF_IDX);
  const unsigned short* __restrict__ wsu = (const unsigned short*)ws;

  const int t = threadIdx.x;
  const int lane = t & 63, w = t >> 6;
  const int wr = w >> 2, wc = w & 3;
  const int bid = blockIdx.x;
  const int bb = bid & 7, qseg = bid >> 3;
  const int chunk0 = bb * 256 + qseg * 8;

  // ---- W fragments -> registers (once; coalesced 1KB/wave frag loads) ----
  short8v w1h[2][4], w1l[2][4], w2h[2][4], w2l[2][4];
#pragma unroll
  for (int ft = 0; ft < 2; ++ft)
#pragma unroll
    for (int ks = 0; ks < 4; ++ks) {
      const int off = ((wc * 2 + ft) * 4 + ks) * 512 + lane * 8;
      w1h[ft][ks] = *(const short8v*)(wsu + OFF16_W1H + off);
      w1l[ft][ks] = *(const short8v*)(wsu + OFF16_W1L + off);
      w2h[ft][ks] = *(const short8v*)(wsu + OFF16_W2H + off);
      w2l[ft][ks] = *(const short8v*)(wsu + OFF16_W2L + off);
    }

  const float c1v0 = (ws + OFF_C1)[wc * 32 + (lane & 15)];
  const float c1v1 = (ws + OFF_C1)[wc * 32 + 16 + (lane & 15)];
  const float c2v0 = (ws + OFF_C2)[wc * 32 + (lane & 15)];
  const float c2v1 = (ws + OFF_C2)[wc * 32 + 16 + (lane & 15)];

  // ---- per-thread A-staging constants ----
  const int row = t >> 3, part8 = t & 7;
  const float* __restrict__ c0p = ws + OFF_C0 + part8 * 16;
  const float4 c0a = *(const float4*)(c0p + 0);
  const float4 c0b = *(const float4*)(c0p + 4);
  const float4 c0c = *(const float4*)(c0p + 8);
  const float4 c0d = *(const float4*)(c0p + 12);

// pack 8 floats (relu'd h1 values) into hi/lo int4 and write swizzled
#define PACK_WRITE_A(base, hv, kc)                              \
  {                                                             \
    unsigned hh[8], ll[8];                                      \
    _Pragma("unroll") for (int e = 0; e < 8; ++e)               \
        split3(hv[e], hh[e], ll[e]);                            \
    int4 hp, lp;                                                \
    hp.x = (int)(hh[0] | (hh[1] << 16));                        \
    hp.y = (int)(hh[2] | (hh[3] << 16));                        \
    hp.z = (int)(hh[4] | (hh[5] << 16));                        \
    hp.w = (int)(hh[6] | (hh[7] << 16));                        \
    lp.x = (int)(ll[0] | (ll[1] << 16));                        \
    lp.y = (int)(ll[2] | (ll[3] << 16));                        \
    lp.z = (int)(ll[4] | (ll[5] << 16));                        \
    lp.w = (int)(ll[6] | (ll[7] << 16));                        \
    const int col = (kc) ^ (row & 7);                           \
    *(int4*)((base) + row * 256 + col * 16) = hp;               \
    *(int4*)((base) + 16384 + row * 256 + col * 16) = lp;       \
  }

  // ---- prologue: stage A[0] into buf0 ----
  {
    const int gp = chunk0 * 64 + row;
    const int mg = idxg[gp];
    const float* __restrict__ ym = y + (long)mg * 128 + part8 * 16;
    const float* __restrict__ yn = y + (long)(gp >> 3) * 128 + part8 * 16;
    const float4 a0 = *(const float4*)(ym + 0);
    const float4 a1 = *(const float4*)(ym + 4);
    const float4 a2 = *(const float4*)(ym + 8);
    const float4 a3 = *(const float4*)(ym + 12);
    const float4 n0 = *(const float4*)(yn + 0);
    const float4 n1 = *(const float4*)(yn + 4);
    const float4 n2 = *(const float4*)(yn + 8);
    const float4 n3 = *(const float4*)(yn + 12);
    float hv0[8] = {relu_f(a0.x - n0.x + c0a.x), relu_f(a0.y - n0.y + c0a.y),
                    relu_f(a0.z - n0.z + c0a.z), relu_f(a0.w - n0.w + c0a.w),
                    relu_f(a1.x - n1.x + c0b.x), relu_f(a1.y - n1.y + c0b.y),
                    relu_f(a1.z - n1.z + c0b.z), relu_f(a1.w - n1.w + c0b.w)};
    float hv1[8] = {relu_f(a2.x - n2.x + c0c.x), relu_f(a2.y - n2.y + c0c.y),
                    relu_f(a2.z - n2.z + c0c.z), relu_f(a2.w - n2.w + c0c.w),
                    relu_f(a3.x - n3.x + c0d.x), relu_f(a3.y - n3.y + c0d.y),
                    relu_f(a3.z - n3.z + c0d.z), relu_f(a3.w - n3.w + c0d.w)};
    PACK_WRITE_A(smem, hv0, part8 * 2)
    PACK_WRITE_A(smem, hv1, part8 * 2 + 1)
  }
  __syncthreads();

#pragma unroll 1
  for (int j = 0; j < 8; ++j) {
    char* __restrict__ Acur = smem + (j & 1) * 32768;
    char* __restrict__ Anxt = smem + ((j & 1) ^ 1) * 32768;

    // issue next chunk's idx early (independent of g1)
    int mg_next = 0, gp_next = 0;
    if (j < 7) {
      gp_next = (chunk0 + j + 1) * 64 + row;
      mg_next = idxg[gp_next];
    }

    // ---- g1: acc = h1 . W1^T (bf16x3), A from Acur ----
    f32x4 acc[2][2];
#pragma unroll
    for (int pt = 0; pt < 2; ++pt)
#pragma unroll
      for (int ft = 0; ft < 2; ++ft) acc[pt][ft] = (f32x4){0.f, 0.f, 0.f, 0.f};
#pragma unroll
    for (int ks = 0; ks < 4; ++ks) {
      const int kc = ks * 4 + (lane >> 4);
#pragma unroll
      for (int pt = 0; pt < 2; ++pt) {
        const int arow = wr * 32 + pt * 16 + (lane & 15);
        const int col = kc ^ (arow & 7);
        const short8v ah = *(const short8v*)(Acur + arow * 256 + col * 16);
        const short8v al =
            *(const short8v*)(Acur + 16384 + arow * 256 + col * 16);
#pragma unroll
        for (int ft = 0; ft < 2; ++ft) {
          acc[pt][ft] = mfma16x16x32bf(al, w1h[ft][ks], acc[pt][ft]);
          acc[pt][ft] = mfma16x16x32bf(ah, w1l[ft][ks], acc[pt][ft]);
          acc[pt][ft] = mfma16x16x32bf(ah, w1h[ft][ks], acc[pt][ft]);
        }
      }
    }

    // ---- issue next chunk's y loads (latency hides under H + g2) ----
    float4 a0, a1, a2, a3, n0, n1, n2, n3;
    if (j < 7) {
      const float* __restrict__ ym = y + (long)mg_next * 128 + part8 * 16;
      const float* __restrict__ yn = y + (long)(gp_next >> 3) * 128 + part8 * 16;
      a0 = *(const float4*)(ym + 0);
      a1 = *(const float4*)(ym + 4);
      a2 = *(const float4*)(ym + 8);
      a3 = *(const float4*)(ym + 12);
      n0 = *(const float4*)(yn + 0);
      n1 = *(const float4*)(yn + 4);
      n2 = *(const float4*)(yn + 8);
      n3 = *(const float4*)(yn + 12);
    }

    // ---- g1 epilogue: relu(acc+c1) -> H (packed u32, swizzled) ----
#pragma unroll
    for (int pt = 0; pt < 2; ++pt)
#pragma unroll
      for (int ft = 0; ft < 2; ++ft) {
        const int fo = wc * 32 + ft * 16 + (lane & 15);
        const int cc = fo >> 2;
        const float cb = ft ? c1v1 : c1v0;
#pragma unroll
        for (int reg = 0; reg < 4; ++reg) {
          const int p = wr * 32 + pt * 16 + (lane >> 4) * 4 + reg;
          const float vv = relu_f(acc[pt][ft][reg] + cb);
          unsigned hh, ll;
          split3(vv, hh, ll);
          H[p * 128 + ((cc ^ (p & 7)) << 2) + (fo & 3)] = (hh << 16) | ll;
        }
      }
    __syncthreads();  // H ready

    // ---- g2: acc2 = h2 . W2^T (bf16x3), A from H ----
    f32x4 acc2[2][2];
#pragma unroll
    for (int pt = 0; pt < 2; ++pt)
#pragma unroll
      for (int ft = 0; ft < 2; ++ft) acc2[pt][ft] = (f32x4){0.f, 0.f, 0.f, 0.f};
#pragma unroll
    for (int ks = 0; ks < 4; ++ks) {
      const int cc0 = ks * 8 + (lane >> 4) * 2;
#pragma unroll
      for (int pt = 0; pt < 2; ++pt) {
        const int p = wr * 32 + pt * 16 + (lane & 15);
        const int4 u0 = *(const int4*)&H[p * 128 + ((cc0 ^ (p & 7)) << 2)];
        const int4 u1 = *(const int4*)&H[p * 128 + (((cc0 + 1) ^ (p & 7)) << 2)];
        const unsigned uu[8] = {(unsigned)u0.x, (unsigned)u0.y, (unsigned)u0.z,
                                (unsigned)u0.w, (unsigned)u1.x, (unsigned)u1.y,
                                (unsigned)u1.z, (unsigned)u1.w};
        short8v ah, al;
#pragma unroll
        for (int e = 0; e < 8; ++e) {
          ah[e] = (short)(uu[e] >> 16);
          al[e] = (short)(uu[e] & 0xFFFFu);
        }
#pragma unroll
        for (int ft = 0; ft < 2; ++ft) {
          acc2[pt][ft] = mfma16x16x32bf(al, w2h[ft][ks], acc2[pt][ft]);
          acc2[pt][ft] = mfma16x16x32bf(ah, w2l[ft][ks], acc2[pt][ft]);
          acc2[pt][ft] = mfma16x16x32bf(ah, w2h[ft][ks], acc2[pt][ft]);
        }
      }
    }
    __syncthreads();  // H reads done (next iter may overwrite H)

    // ---- g2 epilogue: relu+max over 8 pairs/query -> OS rows j*8.. ----
    {
      const int g = lane >> 4;
#pragma unroll
      for (int pt = 0; pt < 2; ++pt)
#pragma unroll
        for (int ft = 0; ft < 2; ++ft) {
          const int fo = wc * 32 + ft * 16 + (lane & 15);
          const float cb = ft ? c2v1 : c2v0;
          const float v0 = relu_f(acc2[pt][ft][0] + cb);
          const float v1 = relu_f(acc2[pt][ft][1] + cb);
          const float v2 = relu_f(acc2[pt][ft][2] + cb);
          const float v3 = relu_f(acc2[pt][ft][3] + cb);
          float m = fmaxf(fmaxf(v0, v1), fmaxf(v2, v3));
          m = fmaxf(m, __shfl_xor(m, 16, 64));
          if ((g & 1) == 0) {
            const int qloc = wr * 4 + pt * 2 + (g >> 1);
            OS[(j * 8 + qloc) * 128 + fo] = m;
          }
        }
    }

    // ---- pack & write A[j+1] into Anxt (loads returned during g2) ----
    if (j < 7) {
      float hv0[8] = {relu_f(a0.x - n0.x + c0a.x), relu_f(a0.y - n0.y + c0a.y),
                      relu_f(a0.z - n0.z + c0a.z), relu_f(a0.w - n0.w + c0a.w),
                      relu_f(a1.x - n1.x + c0b.x), relu_f(a1.y - n1.y + c0b.y),
                      relu_f(a1.z - n1.z + c0b.z), relu_f(a1.w - n1.w + c0b.w)};
      float hv1[8] = {relu_f(a2.x - n2.x + c0c.x), relu_f(a2.y - n2.y + c0c.y),
                      relu_f(a2.z - n2.z + c0c.z), relu_f(a2.w - n2.w + c0c.w),
                      relu_f(a3.x - n3.x + c0d.x), relu_f(a3.y - n3.y + c0d.y),
                      relu_f(a3.z - n3.z + c0d.z), relu_f(a3.w - n3.w + c0d.w)};
      PACK_WRITE_A(Anxt, hv0, part8 * 2)
      PACK_WRITE_A(Anxt, hv1, part8 * 2 + 1)
    }
    __syncthreads();  // A[j+1] ready; OS rows settled
  }

  // ---- final coalesced out-write: OS[64][128] -> out[bb][f][qseg*64..] ----
  {
    const int f = t >> 2, seg = t & 3;
    float* __restrict__ op = out + (long)(bb * 128 + f) * 2048 + qseg * 64 + seg * 16;
#pragma unroll
    for (int u = 0; u < 4; ++u) {
      float4 o;
      o.x = OS[(seg * 16 + u * 4 + 0) * 128 + f];
      o.y = OS[(seg * 16 + u * 4 + 1) * 128 + f];
      o.z = OS[(seg * 16 + u * 4 + 2) * 128 + f];
      o.w = OS[(seg * 16 + u * 4 + 3) * 128 + f];
      *(float4*)(op + u * 4) = o;
    }
  }
}

// ------------------------------- launch ------------------------------------
extern "C" void kernel_launch(void* const* d_in, const int* in_sizes, int n_in,
                              void* d_out, int out_size, void* d_ws,
                              size_t ws_size, hipStream_t stream) {
  (void)in_sizes; (void)n_in; (void)out_size; (void)ws_size;
  const float* x = (const float*)d_in[0];
  const float* w0 = (const float*)d_in[1];
  const float* b0 = (const float*)d_in[2];
  const float* wst = (const float*)d_in[3];
  const float* bst = (const float*)d_in[4];
  const float* g = (const float*)d_in[5];
  const float* be = (const float*)d_in[6];
  const float* bm = (const float*)d_in[7];
  const float* bv = (const float*)d_in[8];
  float* out = (float*)d_out;
  float* ws = (float*)d_ws;

  hipFuncSetAttribute((const void*)fused_kernel,
                      hipFuncAttributeMaxDynamicSharedMemorySize, 131072);

  prep_kernel<<<64, 256, 0, stream>>>(w0, b0, wst, bst, g, be, bm, bv, ws);
  y_kernel<<<NQ * DIMF / 256, 256, 0, stream>>>(x, ws);
  knn_part_kernel<<<1024, 256, 0, stream>>>(x, ws);
  knn_merge_kernel<<<NQ / 64, 256, 0, stream>>>(ws);
  fused_kernel<<<256, 512, 131072, stream>>>(ws, out);
}

// Round 9
// 82.413 us; speedup vs baseline: 2.9693x; 1.2227x over previous
//
#include <hip/hip_runtime.h>

// ---------------------------------------------------------------------------
// FeatureNet: kNN(K=8) relative grouping -> [conv1x1+BN+ReLU] x3 -> max over K
// B=8, N=2048, DIM=128, fp32 in/out.
//
// prep : fold BN; W1/W2 as 4 bf16 planes in MFMA FRAGMENT ORDER; C0/C1/C2; W0F
// knn  : ONE kernel (R9): 512 blocks x 512 thr; block stages its batch's 2048
//        candidates in LDS; 16 lanes/query x 128 cands. Keys-only dual-chain
//        top-8 -> 4 shfl_xor Batcher-merge rounds -> exact global threshold ->
//        rescan+prefix -> write idx[q][8] directly. Also writes y rows.
//        (No partials buffer, no merge kernel, no y kernel.)
// fused: PERSISTENT: 256 blocks (1/CU), 8 chunks each, W in 128 VGPRs.
//        A double-buffered LDS, H own region, OS written coalesced at end.
//        XCD-aligned: block bid -> batch bid&7 (1MB y slice per XCD L2).
// ---------------------------------------------------------------------------

#define EPSF 1e-5f
#define FMAXV 3.402823466e+38f

#define NB 8
#define NN 2048
#define KNBR 8
#define DIMF 128
#define NQ (NB * NN)        // 16384
#define NPAIR (NQ * KNBR)   // 131072

// ws layout. W planes in u16 units [0, 65536) == floats [0, 32768).
#define OFF16_W1H 0          // 16384 u16 (fragment order)
#define OFF16_W1L 16384
#define OFF16_W2H 32768
#define OFF16_W2L 49152
#define OFF_C0 32768         // float units
#define OFF_C1 32896
#define OFF_C2 33024
#define OFF_W0F 33152        // 384
#define OFF_Y 33792          // 2097152 floats
#define OFF_IDX (OFF_Y + NQ * DIMF)   // 131072 ints

typedef __attribute__((ext_vector_type(4))) float f32x4;
typedef __attribute__((ext_vector_type(8))) short short8v;

__device__ __forceinline__ float relu_f(float a) { return fmaxf(a, 0.0f); }

// fp32 -> bf16(hi, RNE) + bf16(lo, trunc of residual)
__device__ __forceinline__ void split3(float f, unsigned& hi, unsigned& lo) {
  const unsigned u = __float_as_uint(f);
  const unsigned h = (u + 0x7FFFu + ((u >> 16) & 1u)) >> 16;
  const float hf = __uint_as_float(h << 16);
  lo = __float_as_uint(f - hf) >> 16;
  hi = h;
}

__device__ __forceinline__ f32x4 mfma16x16x32bf(short8v a, short8v b, f32x4 c) {
  return __builtin_amdgcn_mfma_f32_16x16x32_bf16(a, b, c, 0, 0, 0);
}

// ---- named-scalar selection primitives (R7 lesson: NO array state) ----
// keys-only sorted-8 insert (ascending), 16 ops
#define KINS8(K0, K1, K2, K3, K4, K5, K6, K7, dv)     \
  {                                                   \
    float t_ = (dv), n_;                              \
    n_ = fminf(K0, t_); t_ = fmaxf(K0, t_); K0 = n_;  \
    n_ = fminf(K1, t_); t_ = fmaxf(K1, t_); K1 = n_;  \
    n_ = fminf(K2, t_); t_ = fmaxf(K2, t_); K2 = n_;  \
    n_ = fminf(K3, t_); t_ = fmaxf(K3, t_); K3 = n_;  \
    n_ = fminf(K4, t_); t_ = fmaxf(K4, t_); K4 = n_;  \
    n_ = fminf(K5, t_); t_ = fmaxf(K5, t_); K5 = n_;  \
    n_ = fminf(K6, t_); t_ = fmaxf(K6, t_); K6 = n_;  \
    n_ = fminf(K7, t_); t_ = fmaxf(K7, t_); K7 = n_;  \
  }

#define KCSWAP(a, b)                  \
  {                                   \
    const float mn_ = fminf(a, b);    \
    const float mx_ = fmaxf(a, b);    \
    (a) = mn_; (b) = mx_;             \
  }

// 3-stage bitonic cleanup of a bitonic 8-seq (sorts ascending)
#define KCLEAN8()                                               \
  KCSWAP(k0, k4) KCSWAP(k1, k5) KCSWAP(k2, k6) KCSWAP(k3, k7)   \
  KCSWAP(k0, k2) KCSWAP(k1, k3) KCSWAP(k4, k6) KCSWAP(k5, k7)   \
  KCSWAP(k0, k1) KCSWAP(k2, k3) KCSWAP(k4, k5) KCSWAP(k6, k7)

// Batcher merge with xor-partner's sorted 8 (both sides converge to same list)
#define KMERGE(mv)                                              \
  {                                                             \
    const float q0_ = __shfl_xor(k0, mv, 64);                   \
    const float q1_ = __shfl_xor(k1, mv, 64);                   \
    const float q2_ = __shfl_xor(k2, mv, 64);                   \
    const float q3_ = __shfl_xor(k3, mv, 64);                   \
    const float q4_ = __shfl_xor(k4, mv, 64);                   \
    const float q5_ = __shfl_xor(k5, mv, 64);                   \
    const float q6_ = __shfl_xor(k6, mv, 64);                   \
    const float q7_ = __shfl_xor(k7, mv, 64);                   \
    k0 = fminf(k0, q7_); k1 = fminf(k1, q6_);                   \
    k2 = fminf(k2, q5_); k3 = fminf(k3, q4_);                   \
    k4 = fminf(k4, q3_); k5 = fminf(k5, q2_);                   \
    k6 = fminf(k6, q1_); k7 = fminf(k7, q0_);                   \
    KCLEAN8()                                                   \
  }

// ------------------------------- prep --------------------------------------
// grid 64 x 256. Fragment-order W store:
//   (fo,k) -> tile=(fo>>4)*4+(k>>5), lane=((k>>3)&3)*16+(fo&15), e=k&7
__global__ __launch_bounds__(256) void prep_kernel(
    const float* __restrict__ w0, const float* __restrict__ b0,
    const float* __restrict__ wstk, const float* __restrict__ bstk,
    const float* __restrict__ g, const float* __restrict__ be,
    const float* __restrict__ bm, const float* __restrict__ bv,
    float* __restrict__ ws) {
  const int i = blockIdx.x * 256 + threadIdx.x;  // 16384
  unsigned short* __restrict__ wsh = (unsigned short*)ws;
  {
    const int fo = i >> 7, k = i & 127;
    const float s1 = g[128 + fo] / sqrtf(bv[128 + fo] + EPSF);
    const float s2 = g[256 + fo] / sqrtf(bv[256 + fo] + EPSF);
    unsigned h1, l1, h2, l2;
    split3(wstk[i] * s1, h1, l1);
    split3(wstk[16384 + i] * s2, h2, l2);
    const int dst = ((fo >> 4) * 4 + (k >> 5)) * 512 +
                    (((k >> 3) & 3) * 16 + (fo & 15)) * 8 + (k & 7);
    wsh[OFF16_W1H + dst] = (unsigned short)h1;
    wsh[OFF16_W1L + dst] = (unsigned short)l1;
    wsh[OFF16_W2H + dst] = (unsigned short)h2;
    wsh[OFF16_W2L + dst] = (unsigned short)l2;
  }
  if (blockIdx.x == 0 && threadIdx.x < 128) {
    const int fo = threadIdx.x;
    const float s0 = g[fo] / sqrtf(bv[fo] + EPSF);
    const float s1 = g[128 + fo] / sqrtf(bv[128 + fo] + EPSF);
    const float s2 = g[256 + fo] / sqrtf(bv[256 + fo] + EPSF);
    ws[OFF_C0 + fo] = (b0[fo] - bm[fo]) * s0 + be[fo];
    ws[OFF_C1 + fo] = (bstk[fo] - bm[128 + fo]) * s1 + be[128 + fo];
    ws[OFF_C2 + fo] = (bstk[128 + fo] - bm[256 + fo]) * s2 + be[256 + fo];
    ws[OFF_W0F + 3 * fo + 0] = w0[3 * fo + 0] * s0;
    ws[OFF_W0F + 3 * fo + 1] = w0[3 * fo + 1] * s0;
    ws[OFF_W0F + 3 * fo + 2] = w0[3 * fo + 2] * s0;
  }
}

// ------------------------------- knn (+y) ----------------------------------
// 512 blocks x 512 thr. Block: batch bb=bid>>6, queries qloc0..qloc0+32.
// LDS xs[8][257] float4 (segment-padded: stride 4112B -> 2-way bank alias,
// free). 16 lanes/query (s=t&15), lane covers cands [s*128, s*128+128).
__global__ __launch_bounds__(512) void knn_kernel(const float* __restrict__ x,
                                                  float* __restrict__ ws) {
  __shared__ float4 xs[8][257];
  const int t = threadIdx.x;
  const int bid = blockIdx.x;  // 512
  const int bb = bid >> 6;
  const int qloc0 = (bid & 63) * 32;
  const float* __restrict__ xb = x + bb * 3 * NN;

  // ---- stage all 2048 candidates of this batch ----
#pragma unroll
  for (int k = 0; k < 4; ++k) {
    const int i = t + k * 512;
    const float a0 = xb[i];
    const float a1 = xb[2048 + i];
    const float a2 = xb[4096 + i];
    const float sq = fmaf(a2, a2, fmaf(a1, a1, a0 * a0));
    xs[i >> 8][i & 255] = make_float4(a0, a1, a2, sq);
  }
  __syncthreads();

  const int lane = t & 63;
  const int qi = t >> 4;          // 0..31
  const int s = t & 15;           // candidate slice
  const int n = qloc0 + qi;       // query n within batch
  const int q = bb * NN + n;      // global query
  const float4 qv = xs[n >> 8][n & 255];
  const float qx0 = qv.x, qx1 = qv.y, qx2 = qv.z, sqn = qv.w;

  // ---- y rows: y[q][s*8 .. s*8+8) ----
  {
    const float* __restrict__ W0f = ws + OFF_W0F + s * 24;
    float* __restrict__ yo = ws + OFF_Y + (long)q * 128 + s * 8;
    float yv[8];
#pragma unroll
    for (int f = 0; f < 8; ++f) {
      const float w0 = W0f[f * 3 + 0], w1 = W0f[f * 3 + 1], w2 = W0f[f * 3 + 2];
      yv[f] = fmaf(w2, qx2, fmaf(w1, qx1, w0 * qx0));
    }
    *(float4*)(yo + 0) = make_float4(yv[0], yv[1], yv[2], yv[3]);
    *(float4*)(yo + 4) = make_float4(yv[4], yv[5], yv[6], yv[7]);
  }

  const float4* __restrict__ xrow = &xs[s >> 1][(s & 1) * 128];

  // ---- phase 1: keys-only dual-chain top-8 over 128 cands ----
  float e0 = FMAXV, e1 = FMAXV, e2 = FMAXV, e3 = FMAXV,
        e4 = FMAXV, e5 = FMAXV, e6 = FMAXV, e7 = FMAXV;
  float o0 = FMAXV, o1 = FMAXV, o2 = FMAXV, o3 = FMAXV,
        o4 = FMAXV, o5 = FMAXV, o6 = FMAXV, o7 = FMAXV;
#pragma unroll 2
  for (int mm = 0; mm < 128; mm += 2) {
    const float4 cE = xrow[mm];
    const float4 cO = xrow[mm + 1];
    const float innerE = fmaf(qx2, cE.z, fmaf(qx1, cE.y, qx0 * cE.x));
    const float innerO = fmaf(qx2, cO.z, fmaf(qx1, cO.y, qx0 * cO.x));
    const float dE = (sqn - 2.0f * innerE) + cE.w;
    const float dO = (sqn - 2.0f * innerO) + cO.w;
    KINS8(e0, e1, e2, e3, e4, e5, e6, e7, dE)
    KINS8(o0, o1, o2, o3, o4, o5, o6, o7, dO)
  }

  // low-8 of the two chains (bitonic) -> cleanup -> sorted k0..k7
  float k0 = fminf(e0, o7), k1 = fminf(e1, o6);
  float k2 = fminf(e2, o5), k3 = fminf(e3, o4);
  float k4 = fminf(e4, o3), k5 = fminf(e5, o2);
  float k6 = fminf(e6, o1), k7 = fminf(e7, o0);
  KCLEAN8()

  // ---- cross-lane merge: 16 lanes -> global top-8 keys (all lanes equal) ----
  KMERGE(1) KMERGE(2) KMERGE(4) KMERGE(8)
  const float thr = k7;  // exact global 8th-smallest distance for query q

  // ---- phase 2: rescan own 128, collect hits (index order) ----
  int cnt = 0;
  unsigned long long p0 = 0, p1 = 0;
#pragma unroll 4
  for (int mm = 0; mm < 128; ++mm) {
    const float4 c = xrow[mm];
    const float inner = fmaf(qx2, c.z, fmaf(qx1, c.y, qx0 * c.x));
    const float d = (sqn - 2.0f * inner) + c.w;
    if (d <= thr) {
      if (cnt < 8) {
        p1 = (p1 << 16) | (p0 >> 48);
        p0 = (p0 << 16) | (unsigned long long)(unsigned)(s * 128 + mm);
      }
      ++cnt;
    }
  }
  const int c8 = cnt < 8 ? cnt : 8;

  // prefix over the 16-lane group (ascending s == ascending candidate index)
  const int gb = lane & ~15;
  int off = 0;
#pragma unroll
  for (int g2 = 0; g2 < 15; ++g2) {
    const int cg = __shfl(c8, gb + g2, 64);
    off += (g2 < s) ? cg : 0;
  }

  int* __restrict__ idxg = (int*)(ws + OFF_IDX);
  for (int k = 0; k < c8; ++k) {
    const int pos = off + k;
    if (pos < 8) {
      const int sh = c8 - 1 - k;
      const unsigned v = (sh < 4) ? (unsigned)(p0 >> (16 * sh))
                                  : (unsigned)(p1 >> (16 * (sh - 4)));
      idxg[q * 8 + pos] = bb * NN + (int)(v & 0xFFFFu);
    }
  }
}

// --------------------------- persistent fused ------------------------------
// 256 blocks x 512 thr (8 waves: wr=w>>2 pair-half, wc=w&3 fo-slice).
// Block bid: batch bb=bid&7, queries qseg*64..+64 (qseg=bid>>3), 8 chunks of
// 64 pairs. LDS 128KB: A dbuf 2x32KB @0, H 32KB @64K, OS 32KB @96K.
// A-plane 16B chunks swizzled col = kc ^ (row&7); H 16B chunks cc ^= (p&7).
__global__ __launch_bounds__(512, 2) void fused_kernel(float* __restrict__ ws,
                                                       float* __restrict__ out) {
  extern __shared__ char smem[];
  unsigned* __restrict__ H = (unsigned*)(smem + 65536);
  float* __restrict__ OS = (float*)(smem + 98304);

  const float* __restrict__ y = ws + OFF_Y;
  const int* __restrict__ idxg = (const int*)(ws + OFF_IDX);
  const unsigned short* __restrict__ wsu = (const unsigned short*)ws;

  const int t = threadIdx.x;
  const int lane = t & 63, w = t >> 6;
  const int wr = w >> 2, wc = w & 3;
  const int bid = blockIdx.x;
  const int bb = bid & 7, qseg = bid >> 3;
  const int chunk0 = bb * 256 + qseg * 8;

  // ---- W fragments -> registers (once; coalesced 1KB/wave frag loads) ----
  short8v w1h[2][4], w1l[2][4], w2h[2][4], w2l[2][4];
#pragma unroll
  for (int ft = 0; ft < 2; ++ft)
#pragma unroll
    for (int ks = 0; ks < 4; ++ks) {
      const int off = ((wc * 2 + ft) * 4 + ks) * 512 + lane * 8;
      w1h[ft][ks] = *(const short8v*)(wsu + OFF16_W1H + off);
      w1l[ft][ks] = *(const short8v*)(wsu + OFF16_W1L + off);
      w2h[ft][ks] = *(const short8v*)(wsu + OFF16_W2H + off);
      w2l[ft][ks] = *(const short8v*)(wsu + OFF16_W2L + off);
    }

  const float c1v0 = (ws + OFF_C1)[wc * 32 + (lane & 15)];
  const float c1v1 = (ws + OFF_C1)[wc * 32 + 16 + (lane & 15)];
  const float c2v0 = (ws + OFF_C2)[wc * 32 + (lane & 15)];
  const float c2v1 = (ws + OFF_C2)[wc * 32 + 16 + (lane & 15)];

  // ---- per-thread A-staging constants ----
  const int row = t >> 3, part8 = t & 7;
  const float* __restrict__ c0p = ws + OFF_C0 + part8 * 16;
  const float4 c0a = *(const float4*)(c0p + 0);
  const float4 c0b = *(const float4*)(c0p + 4);
  const float4 c0c = *(const float4*)(c0p + 8);
  const float4 c0d = *(const float4*)(c0p + 12);

// pack 8 floats (relu'd h1 values) into hi/lo int4 and write swizzled
#define PACK_WRITE_A(base, hv, kc)                              \
  {                                                             \
    unsigned hh[8], ll[8];                                      \
    _Pragma("unroll") for (int e = 0; e < 8; ++e)               \
        split3(hv[e], hh[e], ll[e]);                            \
    int4 hp, lp;                                                \
    hp.x = (int)(hh[0] | (hh[1] << 16));                        \
    hp.y = (int)(hh[2] | (hh[3] << 16));                        \
    hp.z = (int)(hh[4] | (hh[5] << 16));                        \
    hp.w = (int)(hh[6] | (hh[7] << 16));                        \
    lp.x = (int)(ll[0] | (ll[1] << 16));                        \
    lp.y = (int)(ll[2] | (ll[3] << 16));                        \
    lp.z = (int)(ll[4] | (ll[5] << 16));                        \
    lp.w = (int)(ll[6] | (ll[7] << 16));                        \
    const int col = (kc) ^ (row & 7);                           \
    *(int4*)((base) + row * 256 + col * 16) = hp;               \
    *(int4*)((base) + 16384 + row * 256 + col * 16) = lp;       \
  }

  // ---- prologue: stage A[0] into buf0 ----
  {
    const int gp = chunk0 * 64 + row;
    const int mg = idxg[gp];
    const float* __restrict__ ym = y + (long)mg * 128 + part8 * 16;
    const float* __restrict__ yn = y + (long)(gp >> 3) * 128 + part8 * 16;
    const float4 a0 = *(const float4*)(ym + 0);
    const float4 a1 = *(const float4*)(ym + 4);
    const float4 a2 = *(const float4*)(ym + 8);
    const float4 a3 = *(const float4*)(ym + 12);
    const float4 n0 = *(const float4*)(yn + 0);
    const float4 n1 = *(const float4*)(yn + 4);
    const float4 n2 = *(const float4*)(yn + 8);
    const float4 n3 = *(const float4*)(yn + 12);
    float hv0[8] = {relu_f(a0.x - n0.x + c0a.x), relu_f(a0.y - n0.y + c0a.y),
                    relu_f(a0.z - n0.z + c0a.z), relu_f(a0.w - n0.w + c0a.w),
                    relu_f(a1.x - n1.x + c0b.x), relu_f(a1.y - n1.y + c0b.y),
                    relu_f(a1.z - n1.z + c0b.z), relu_f(a1.w - n1.w + c0b.w)};
    float hv1[8] = {relu_f(a2.x - n2.x + c0c.x), relu_f(a2.y - n2.y + c0c.y),
                    relu_f(a2.z - n2.z + c0c.z), relu_f(a2.w - n2.w + c0c.w),
                    relu_f(a3.x - n3.x + c0d.x), relu_f(a3.y - n3.y + c0d.y),
                    relu_f(a3.z - n3.z + c0d.z), relu_f(a3.w - n3.w + c0d.w)};
    PACK_WRITE_A(smem, hv0, part8 * 2)
    PACK_WRITE_A(smem, hv1, part8 * 2 + 1)
  }
  __syncthreads();

#pragma unroll 1
  for (int j = 0; j < 8; ++j) {
    char* __restrict__ Acur = smem + (j & 1) * 32768;
    char* __restrict__ Anxt = smem + ((j & 1) ^ 1) * 32768;

    // issue next chunk's idx early (independent of g1)
    int mg_next = 0, gp_next = 0;
    if (j < 7) {
      gp_next = (chunk0 + j + 1) * 64 + row;
      mg_next = idxg[gp_next];
    }

    // ---- g1: acc = h1 . W1^T (bf16x3), A from Acur ----
    f32x4 acc[2][2];
#pragma unroll
    for (int pt = 0; pt < 2; ++pt)
#pragma unroll
      for (int ft = 0; ft < 2; ++ft) acc[pt][ft] = (f32x4){0.f, 0.f, 0.f, 0.f};
#pragma unroll
    for (int ks = 0; ks < 4; ++ks) {
      const int kc = ks * 4 + (lane >> 4);
#pragma unroll
      for (int pt = 0; pt < 2; ++pt) {
        const int arow = wr * 32 + pt * 16 + (lane & 15);
        const int col = kc ^ (arow & 7);
        const short8v ah = *(const short8v*)(Acur + arow * 256 + col * 16);
        const short8v al =
            *(const short8v*)(Acur + 16384 + arow * 256 + col * 16);
#pragma unroll
        for (int ft = 0; ft < 2; ++ft) {
          acc[pt][ft] = mfma16x16x32bf(al, w1h[ft][ks], acc[pt][ft]);
          acc[pt][ft] = mfma16x16x32bf(ah, w1l[ft][ks], acc[pt][ft]);
          acc[pt][ft] = mfma16x16x32bf(ah, w1h[ft][ks], acc[pt][ft]);
        }
      }
    }

    // ---- issue next chunk's y loads (latency hides under H + g2) ----
    float4 a0, a1, a2, a3, n0, n1, n2, n3;
    if (j < 7) {
      const float* __restrict__ ym = y + (long)mg_next * 128 + part8 * 16;
      const float* __restrict__ yn = y + (long)(gp_next >> 3) * 128 + part8 * 16;
      a0 = *(const float4*)(ym + 0);
      a1 = *(const float4*)(ym + 4);
      a2 = *(const float4*)(ym + 8);
      a3 = *(const float4*)(ym + 12);
      n0 = *(const float4*)(yn + 0);
      n1 = *(const float4*)(yn + 4);
      n2 = *(const float4*)(yn + 8);
      n3 = *(const float4*)(yn + 12);
    }

    // ---- g1 epilogue: relu(acc+c1) -> H (packed u32, swizzled) ----
#pragma unroll
    for (int pt = 0; pt < 2; ++pt)
#pragma unroll
      for (int ft = 0; ft < 2; ++ft) {
        const int fo = wc * 32 + ft * 16 + (lane & 15);
        const int cc = fo >> 2;
        const float cb = ft ? c1v1 : c1v0;
#pragma unroll
        for (int reg = 0; reg < 4; ++reg) {
          const int p = wr * 32 + pt * 16 + (lane >> 4) * 4 + reg;
          const float vv = relu_f(acc[pt][ft][reg] + cb);
          unsigned hh, ll;
          split3(vv, hh, ll);
          H[p * 128 + ((cc ^ (p & 7)) << 2) + (fo & 3)] = (hh << 16) | ll;
        }
      }
    __syncthreads();  // H ready

    // ---- g2: acc2 = h2 . W2^T (bf16x3), A from H ----
    f32x4 acc2[2][2];
#pragma unroll
    for (int pt = 0; pt < 2; ++pt)
#pragma unroll
      for (int ft = 0; ft < 2; ++ft) acc2[pt][ft] = (f32x4){0.f, 0.f, 0.f, 0.f};
#pragma unroll
    for (int ks = 0; ks < 4; ++ks) {
      const int cc0 = ks * 8 + (lane >> 4) * 2;
#pragma unroll
      for (int pt = 0; pt < 2; ++pt) {
        const int p = wr * 32 + pt * 16 + (lane & 15);
        const int4 u0 = *(const int4*)&H[p * 128 + ((cc0 ^ (p & 7)) << 2)];
        const int4 u1 = *(const int4*)&H[p * 128 + (((cc0 + 1) ^ (p & 7)) << 2)];
        const unsigned uu[8] = {(unsigned)u0.x, (unsigned)u0.y, (unsigned)u0.z,
                                (unsigned)u0.w, (unsigned)u1.x, (unsigned)u1.y,
                                (unsigned)u1.z, (unsigned)u1.w};
        short8v ah, al;
#pragma unroll
        for (int e = 0; e < 8; ++e) {
          ah[e] = (short)(uu[e] >> 16);
          al[e] = (short)(uu[e] & 0xFFFFu);
        }
#pragma unroll
        for (int ft = 0; ft < 2; ++ft) {
          acc2[pt][ft] = mfma16x16x32bf(al, w2h[ft][ks], acc2[pt][ft]);
          acc2[pt][ft] = mfma16x16x32bf(ah, w2l[ft][ks], acc2[pt][ft]);
          acc2[pt][ft] = mfma16x16x32bf(ah, w2h[ft][ks], acc2[pt][ft]);
        }
      }
    }
    __syncthreads();  // H reads done (next iter may overwrite H)

    // ---- g2 epilogue: relu+max over 8 pairs/query -> OS rows j*8.. ----
    {
      const int g = lane >> 4;
#pragma unroll
      for (int pt = 0; pt < 2; ++pt)
#pragma unroll
        for (int ft = 0; ft < 2; ++ft) {
          const int fo = wc * 32 + ft * 16 + (lane & 15);
          const float cb = ft ? c2v1 : c2v0;
          const float v0 = relu_f(acc2[pt][ft][0] + cb);
          const float v1 = relu_f(acc2[pt][ft][1] + cb);
          const float v2 = relu_f(acc2[pt][ft][2] + cb);
          const float v3 = relu_f(acc2[pt][ft][3] + cb);
          float m = fmaxf(fmaxf(v0, v1), fmaxf(v2, v3));
          m = fmaxf(m, __shfl_xor(m, 16, 64));
          if ((g & 1) == 0) {
            const int qloc = wr * 4 + pt * 2 + (g >> 1);
            OS[(j * 8 + qloc) * 128 + fo] = m;
          }
        }
    }

    // ---- pack & write A[j+1] into Anxt (loads returned during g2) ----
    if (j < 7) {
      float hv0[8] = {relu_f(a0.x - n0.x + c0a.x), relu_f(a0.y - n0.y + c0a.y),
                      relu_f(a0.z - n0.z + c0a.z), relu_f(a0.w - n0.w + c0a.w),
                      relu_f(a1.x - n1.x + c0b.x), relu_f(a1.y - n1.y + c0b.y),
                      relu_f(a1.z - n1.z + c0b.z), relu_f(a1.w - n1.w + c0b.w)};
      float hv1[8] = {relu_f(a2.x - n2.x + c0c.x), relu_f(a2.y - n2.y + c0c.y),
                      relu_f(a2.z - n2.z + c0c.z), relu_f(a2.w - n2.w + c0c.w),
                      relu_f(a3.x - n3.x + c0d.x), relu_f(a3.y - n3.y + c0d.y),
                      relu_f(a3.z - n3.z + c0d.z), relu_f(a3.w - n3.w + c0d.w)};
      PACK_WRITE_A(Anxt, hv0, part8 * 2)
      PACK_WRITE_A(Anxt, hv1, part8 * 2 + 1)
    }
    __syncthreads();  // A[j+1] ready; OS rows settled
  }

  // ---- final coalesced out-write: OS[64][128] -> out[bb][f][qseg*64..] ----
  {
    const int f = t >> 2, seg = t & 3;
    float* __restrict__ op = out + (long)(bb * 128 + f) * 2048 + qseg * 64 + seg * 16;
#pragma unroll
    for (int u = 0; u < 4; ++u) {
      float4 o;
      o.x = OS[(seg * 16 + u * 4 + 0) * 128 + f];
      o.y = OS[(seg * 16 + u * 4 + 1) * 128 + f];
      o.z = OS[(seg * 16 + u * 4 + 2) * 128 + f];
      o.w = OS[(seg * 16 + u * 4 + 3) * 128 + f];
      *(float4*)(op + u * 4) = o;
    }
  }
}

// ------------------------------- launch ------------------------------------
extern "C" void kernel_launch(void* const* d_in, const int* in_sizes, int n_in,
                              void* d_out, int out_size, void* d_ws,
                              size_t ws_size, hipStream_t stream) {
  (void)in_sizes; (void)n_in; (void)out_size; (void)ws_size;
  const float* x = (const float*)d_in[0];
  const float* w0 = (const float*)d_in[1];
  const float* b0 = (const float*)d_in[2];
  const float* wst = (const float*)d_in[3];
  const float* bst = (const float*)d_in[4];
  const float* g = (const float*)d_in[5];
  const float* be = (const float*)d_in[6];
  const float* bm = (const float*)d_in[7];
  const float* bv = (const float*)d_in[8];
  float* out = (float*)d_out;
  float* ws = (float*)d_ws;

  hipFuncSetAttribute((const void*)fused_kernel,
                      hipFuncAttributeMaxDynamicSharedMemorySize, 131072);

  prep_kernel<<<64, 256, 0, stream>>>(w0, b0, wst, bst, g, be, bm, bv, ws);
  knn_kernel<<<512, 512, 0, stream>>>(x, ws);
  fused_kernel<<<256, 512, 131072, stream>>>(ws, out);
}